// Round 1
// baseline (415.613 us; speedup 1.0000x reference)
//
#include <hip/hip_runtime.h>

// Siamese GeoCheby: 3 branches x (ChebConv K=2 -> relu -> ChebConv K=2 -> fc1+relu -> fc2)
// Key identity: segment_sum(norm * x[col]) @ W == segment_sum(norm * (x@W)[col])
// so the sparse aggregation runs on H=16 features, not F=268.

#define NN   268
#define EE   8576
#define NG   192          // 3 branches * 64 graphs
#define FDIM 4288         // 268*16

// workspace layout (float offsets)
#define XW0_OFF  0
#define XW1_OFF  (XW0_OFF + (size_t)NG * FDIM)          //  823296
#define CNRM_OFF (XW1_OFF + (size_t)NG * FDIM)          // 1646592
#define CCOL_OFF (CNRM_OFF + (size_t)NG * EE)           // 3293184
#define OFFS_OFF (CCOL_OFF + (size_t)NG * EE)           // 4939776
#define F_OFF    (OFFS_OFF + (size_t)NG * (NN + 1))     // 4991424
#define R1_OFF   (F_OFF + (size_t)NG * FDIM)            // 5814720
// total = R1_OFF + NG*1024 = 6011328 floats (~24 MB)

// ---------------------------------------------------------------------------
// K1: per-graph degree + rsqrt norm + CSR build (counting sort by row)
// ---------------------------------------------------------------------------
__global__ __launch_bounds__(256) void k_csr(
    const int* __restrict__ ei0, const int* __restrict__ ei1, const int* __restrict__ ei2,
    const float* __restrict__ ea0, const float* __restrict__ ea1, const float* __restrict__ ea2,
    float* __restrict__ cnrm, int* __restrict__ ccol, int* __restrict__ offs)
{
    const int g = blockIdx.x;             // 0..191
    const int br = g >> 6, b = g & 63;
    const int*   ei = (br == 0) ? ei0 : (br == 1) ? ei1 : ei2;
    const float* ea = (br == 0) ? ea0 : (br == 1) ? ea1 : ea2;
    const int*   rowp = ei + (size_t)b * (2 * EE);
    const int*   colp = rowp + EE;
    const float* eap  = ea + (size_t)b * EE;

    __shared__ float degS[NN];
    __shared__ int   cntS[NN];
    __shared__ int   offS[NN + 1];
    __shared__ int   curS[NN];
    const int tid = threadIdx.x;

    for (int n = tid; n < NN; n += 256) { degS[n] = 0.f; cntS[n] = 0; }
    __syncthreads();
    for (int e = tid; e < EE; e += 256) {
        const int r = rowp[e];
        atomicAdd(&degS[r], eap[e]);
        atomicAdd(&cntS[r], 1);
    }
    __syncthreads();
    if (tid == 0) {
        int s = 0; offS[0] = 0;
        for (int n = 0; n < NN; ++n) { s += cntS[n]; offS[n + 1] = s; }
    }
    __syncthreads();
    for (int n = tid; n < NN; n += 256) {
        curS[n] = offS[n];
        const float d = degS[n];
        degS[n] = (d > 0.f) ? rsqrtf(d) : 0.f;   // degS becomes dis
    }
    __syncthreads();
    float* cn = cnrm + (size_t)g * EE;
    int*   cc = ccol + (size_t)g * EE;
    for (int e = tid; e < EE; e += 256) {
        const int r = rowp[e], c = colp[e];
        const float w = eap[e];
        const int pos = atomicAdd(&curS[r], 1);
        cc[pos] = c;
        cn[pos] = -w * degS[r] * degS[c];
    }
    int* og = offs + g * (NN + 1);
    for (int n = tid; n <= NN; n += 256) og[n] = offS[n];
}

// ---------------------------------------------------------------------------
// K2: xw = x @ [w0 | w1]   (batched, M=268 rows per graph, K=268, Ncols=32)
// tile: 128 rows x 32 cols, Kc=32 chunks, 4x4 register tile per thread
// ---------------------------------------------------------------------------
__global__ __launch_bounds__(256) void k_xw(
    const float* __restrict__ x0, const float* __restrict__ x1, const float* __restrict__ x2,
    const float* __restrict__ gc1w, float* __restrict__ xw0, float* __restrict__ xw1)
{
    const int g = blockIdx.y;
    const int br = g >> 6, b = g & 63;
    const float* x = ((br == 0) ? x0 : (br == 1) ? x1 : x2) + (size_t)b * (NN * NN);
    const int row0 = blockIdx.x * 128;

    __shared__ float wsT[32][276];   // wsT[j][k] = Wcat^T, padded (276%32=20 -> 2-way max)
    __shared__ float xs[128][36];    // 32-k chunk, stride 36 (144B, 16B aligned)

    const int tid = threadIdx.x;
    // load Wcat transposed (once per block; w is 34KB, L1/L2 resident)
    for (int j = 0; j < 32; ++j) {
        const int sel = j >> 4, jj = j & 15;
        for (int k = tid; k < 276; k += 256)
            wsT[j][k] = (k < NN) ? gc1w[sel * FDIM + k * 16 + jj] : 0.f;
    }

    const int mt = tid >> 3;   // 0..31 : rows mt + 32*i
    const int jt = tid & 7;    // cols jt + 8*j
    float acc[4][4];
#pragma unroll
    for (int i = 0; i < 4; ++i)
#pragma unroll
        for (int j = 0; j < 4; ++j) acc[i][j] = 0.f;

    for (int kb = 0; kb < NN; kb += 32) {
        __syncthreads();
        for (int idx = tid; idx < 1024; idx += 256) {
            const int r = idx >> 3, q = idx & 7;
            const int gr = row0 + r, gk = kb + q * 4;
            float4 v = make_float4(0.f, 0.f, 0.f, 0.f);
            if (gr < NN && gk <= NN - 4)
                v = *(const float4*)(x + (size_t)gr * NN + gk);
            *(float4*)&xs[r][q * 4] = v;
        }
        __syncthreads();
        const int kq4 = (kb + 32 <= NN) ? 8 : ((NN - kb + 3) >> 2);  // 8 or 3
        for (int kq = 0; kq < kq4; ++kq) {
            float4 av[4], bv[4];
#pragma unroll
            for (int i = 0; i < 4; ++i) av[i] = *(const float4*)&xs[mt + 32 * i][kq * 4];
#pragma unroll
            for (int j = 0; j < 4; ++j) bv[j] = *(const float4*)&wsT[jt + 8 * j][kb + kq * 4];
#pragma unroll
            for (int i = 0; i < 4; ++i)
#pragma unroll
                for (int j = 0; j < 4; ++j)
                    acc[i][j] += av[i].x * bv[j].x + av[i].y * bv[j].y +
                                 av[i].z * bv[j].z + av[i].w * bv[j].w;
        }
    }
#pragma unroll
    for (int i = 0; i < 4; ++i) {
        const int r = row0 + mt + 32 * i;
        if (r >= NN) continue;
#pragma unroll
        for (int j = 0; j < 4; ++j) {
            const int c = jt + 8 * j;
            const float v = acc[i][j];
            if (c < 16) xw0[((size_t)g * NN + r) * 16 + c] = v;
            else        xw1[((size_t)g * NN + r) * 16 + (c - 16)] = v;
        }
    }
}

// ---------------------------------------------------------------------------
// K3: per-graph fused conv: gather1 -> relu(h) -> h@w4_1 -> gather2 -> +h@w4_0+b4
// ---------------------------------------------------------------------------
__global__ __launch_bounds__(256) void k_conv(
    const float* __restrict__ xw0, const float* __restrict__ xw1,
    const float* __restrict__ cnrm, const int* __restrict__ ccol,
    const int* __restrict__ offs, const float* __restrict__ gc1b,
    const float* __restrict__ gc4w, const float* __restrict__ gc4b,
    float* __restrict__ fout)
{
    const int g = blockIdx.x;
    __shared__ __align__(16) float A_s[FDIM];   // xw1, later reused for H1 = h@w4_1
    __shared__ __align__(16) float S_s[FDIM];   // h
    __shared__ int   off_s[NN + 1];
    __shared__ float w4_s[512];
    __shared__ __align__(16) float b1_s[16];
    __shared__ __align__(16) float b4_s[16];
    const int tid = threadIdx.x;

    {
        const float4* src = (const float4*)(xw1 + (size_t)g * FDIM);
        float4* dst = (float4*)A_s;
        for (int i = tid; i < FDIM / 4; i += 256) dst[i] = src[i];
    }
    for (int i = tid; i < NN + 1; i += 256) off_s[i] = offs[g * (NN + 1) + i];
    for (int i = tid; i < 512; i += 256) w4_s[i] = gc4w[i];
    if (tid < 16) { b1_s[tid] = gc1b[tid]; b4_s[tid] = gc4b[tid]; }
    __syncthreads();

    const float* cn = cnrm + (size_t)g * EE;
    const int*   cc = ccol + (size_t)g * EE;
    const int j4 = tid & 3, nl = tid >> 2;
    const float4* xw0g = (const float4*)(xw0 + (size_t)g * FDIM);
    const float4* A4 = (const float4*)A_s;

    // conv1 gather: h = relu(xw0 + sum norm*xw1[col] + b1)
    for (int n = nl; n < NN; n += 64) {
        const int s = off_s[n], e = off_s[n + 1];
        float ax = 0.f, ay = 0.f, az = 0.f, aw = 0.f;
        for (int i = s; i < e; ++i) {
            const int c = cc[i];
            const float wv = cn[i];
            const float4 av = A4[c * 4 + j4];
            ax += wv * av.x; ay += wv * av.y; az += wv * av.z; aw += wv * av.w;
        }
        const float4 xv = xw0g[n * 4 + j4];
        const float4 bv = ((const float4*)b1_s)[j4];
        float4 h;
        h.x = fmaxf(xv.x + ax + bv.x, 0.f);
        h.y = fmaxf(xv.y + ay + bv.y, 0.f);
        h.z = fmaxf(xv.z + az + bv.z, 0.f);
        h.w = fmaxf(xv.w + aw + bv.w, 0.f);
        ((float4*)S_s)[n * 4 + j4] = h;
    }
    __syncthreads();

    // H1 = h @ w4[1]  -> overwrite A_s
    for (int idx = tid; idx < FDIM; idx += 256) {
        const int n = idx >> 4, j = idx & 15;
        float a1 = 0.f;
        const float* srow = &S_s[n * 16];
#pragma unroll
        for (int k = 0; k < 16; ++k) a1 += srow[k] * w4_s[256 + k * 16 + j];
        A_s[idx] = a1;
    }
    __syncthreads();

    // conv2: out = h@w4[0] + b4 + sum norm*H1[col]
    float4* fg = (float4*)(fout + (size_t)g * FDIM);
    for (int n = nl; n < NN; n += 64) {
        const int s = off_s[n], e = off_s[n + 1];
        float ax = 0.f, ay = 0.f, az = 0.f, aw = 0.f;
        for (int i = s; i < e; ++i) {
            const int c = cc[i];
            const float wv = cn[i];
            const float4 av = A4[c * 4 + j4];
            ax += wv * av.x; ay += wv * av.y; az += wv * av.z; aw += wv * av.w;
        }
        float h0[4];
#pragma unroll
        for (int c2 = 0; c2 < 4; ++c2) h0[c2] = b4_s[j4 * 4 + c2];
        const float* srow = &S_s[n * 16];
#pragma unroll
        for (int k = 0; k < 16; ++k) {
            const float sv = srow[k];
#pragma unroll
            for (int c2 = 0; c2 < 4; ++c2) h0[c2] += sv * w4_s[k * 16 + j4 * 4 + c2];
        }
        float4 o;
        o.x = h0[0] + ax; o.y = h0[1] + ay; o.z = h0[2] + az; o.w = h0[3] + aw;
        fg[n * 4 + j4] = o;
    }
}

// ---------------------------------------------------------------------------
// K4: fc1 raw: r1[192][1024] += f[192][4288] @ fc1_w[1024][4288]^T  (split-K 16)
// tile 128x128, 8x8 register tile, atomicAdd into zeroed r1
// ---------------------------------------------------------------------------
__global__ __launch_bounds__(256) void k_fc1(
    const float* __restrict__ f, const float* __restrict__ w, float* __restrict__ r1)
{
    const int m0 = blockIdx.x * 128;
    const int n0 = blockIdx.y * 128;
    const int kbase = blockIdx.z * 268;
    __shared__ float fs[128][36];
    __shared__ float wss[128][36];
    const int tid = threadIdx.x;
    const int mt = tid & 15, nt = tid >> 4;
    float acc[8][8];
#pragma unroll
    for (int i = 0; i < 8; ++i)
#pragma unroll
        for (int j = 0; j < 8; ++j) acc[i][j] = 0.f;

    for (int kc = 0; kc < 268; kc += 32) {
        const int klen = (268 - kc < 32) ? (268 - kc) : 32;
        __syncthreads();
        for (int idx = tid; idx < 1024; idx += 256) {
            const int r = idx >> 3, q = idx & 7;
            const int gk = kbase + kc + q * 4;
            float4 fv = make_float4(0.f, 0.f, 0.f, 0.f);
            float4 wv = make_float4(0.f, 0.f, 0.f, 0.f);
            if (q * 4 < klen) {
                const int gm = m0 + r;
                if (gm < NG) fv = *(const float4*)(f + (size_t)gm * FDIM + gk);
                wv = *(const float4*)(w + (size_t)(n0 + r) * FDIM + gk);
            }
            *(float4*)&fs[r][q * 4] = fv;
            *(float4*)&wss[r][q * 4] = wv;
        }
        __syncthreads();
        const int kq4 = (klen + 3) >> 2;   // 8 or 3
        for (int kq = 0; kq < kq4; ++kq) {
            float4 av[8], bv[8];
#pragma unroll
            for (int i = 0; i < 8; ++i) av[i] = *(const float4*)&fs[mt + 16 * i][kq * 4];
#pragma unroll
            for (int j = 0; j < 8; ++j) bv[j] = *(const float4*)&wss[nt + 16 * j][kq * 4];
#pragma unroll
            for (int i = 0; i < 8; ++i)
#pragma unroll
                for (int j = 0; j < 8; ++j)
                    acc[i][j] += av[i].x * bv[j].x + av[i].y * bv[j].y +
                                 av[i].z * bv[j].z + av[i].w * bv[j].w;
        }
    }
#pragma unroll
    for (int i = 0; i < 8; ++i) {
        const int gm = m0 + mt + 16 * i;
        if (gm >= NG) continue;
#pragma unroll
        for (int j = 0; j < 8; ++j)
            atomicAdd(&r1[(size_t)gm * 1024 + n0 + nt + 16 * j], acc[i][j]);
    }
}

// ---------------------------------------------------------------------------
// K5: fc2: out = relu(r1 + fc1_b) @ fc2_w^T + fc2_b   (split-K 8, bias on kz==0)
// ---------------------------------------------------------------------------
__global__ __launch_bounds__(256) void k_fc2(
    const float* __restrict__ r1, const float* __restrict__ b1,
    const float* __restrict__ w2, const float* __restrict__ b2,
    float* __restrict__ out)
{
    const int m0 = blockIdx.x * 64;
    const int n0 = blockIdx.y * 64;
    const int kb = blockIdx.z * 128;
    __shared__ float rs[64][68];
    __shared__ float wss[64][68];
    const int tid = threadIdx.x;
    const int mt = tid & 15, nt = tid >> 4;
    float acc[4][4];
#pragma unroll
    for (int i = 0; i < 4; ++i)
#pragma unroll
        for (int j = 0; j < 4; ++j) acc[i][j] = 0.f;

    for (int kc = 0; kc < 128; kc += 64) {
        __syncthreads();
        for (int idx = tid; idx < 1024; idx += 256) {
            const int r = idx >> 4, q = idx & 15;
            const int gk = kb + kc + q * 4;
            const int gm = m0 + r;
            float4 rv = make_float4(0.f, 0.f, 0.f, 0.f);
            if (gm < NG) {
                const float4 raw = *(const float4*)(r1 + (size_t)gm * 1024 + gk);
                const float4 bb  = *(const float4*)(b1 + gk);
                rv.x = fmaxf(raw.x + bb.x, 0.f);
                rv.y = fmaxf(raw.y + bb.y, 0.f);
                rv.z = fmaxf(raw.z + bb.z, 0.f);
                rv.w = fmaxf(raw.w + bb.w, 0.f);
            }
            *(float4*)&rs[r][q * 4] = rv;
            *(float4*)&wss[r][q * 4] = *(const float4*)(w2 + (size_t)(n0 + r) * 1024 + gk);
        }
        __syncthreads();
        for (int kq = 0; kq < 16; ++kq) {
            float4 av[4], bv[4];
#pragma unroll
            for (int i = 0; i < 4; ++i) av[i] = *(const float4*)&rs[mt + 16 * i][kq * 4];
#pragma unroll
            for (int j = 0; j < 4; ++j) bv[j] = *(const float4*)&wss[nt + 16 * j][kq * 4];
#pragma unroll
            for (int i = 0; i < 4; ++i)
#pragma unroll
                for (int j = 0; j < 4; ++j)
                    acc[i][j] += av[i].x * bv[j].x + av[i].y * bv[j].y +
                                 av[i].z * bv[j].z + av[i].w * bv[j].w;
        }
    }
    const bool addb = (blockIdx.z == 0);
#pragma unroll
    for (int i = 0; i < 4; ++i) {
        const int gm = m0 + mt + 16 * i;
        if (gm >= NG) continue;
#pragma unroll
        for (int j = 0; j < 4; ++j) {
            const int gn = n0 + nt + 16 * j;
            float v = acc[i][j];
            if (addb) v += b2[gn];
            atomicAdd(&out[(size_t)gm * 512 + gn], v);
        }
    }
}

// ---------------------------------------------------------------------------
extern "C" void kernel_launch(void* const* d_in, const int* in_sizes, int n_in,
                              void* d_out, int out_size, void* d_ws, size_t ws_size,
                              hipStream_t stream)
{
    const float* x0   = (const float*)d_in[0];
    const float* x1   = (const float*)d_in[1];
    const float* x2   = (const float*)d_in[2];
    const int*   ei0  = (const int*)d_in[3];
    const int*   ei1  = (const int*)d_in[4];
    const int*   ei2  = (const int*)d_in[5];
    const float* ea0  = (const float*)d_in[6];
    const float* ea1  = (const float*)d_in[7];
    const float* ea2  = (const float*)d_in[8];
    const float* gc1w = (const float*)d_in[9];
    const float* gc1b = (const float*)d_in[10];
    const float* gc4w = (const float*)d_in[11];
    const float* gc4b = (const float*)d_in[12];
    const float* fc1w = (const float*)d_in[13];
    const float* fc1b = (const float*)d_in[14];
    const float* fc2w = (const float*)d_in[15];
    const float* fc2b = (const float*)d_in[16];

    float* ws   = (float*)d_ws;
    float* xw0  = ws + XW0_OFF;
    float* xw1  = ws + XW1_OFF;
    float* cnrm = ws + CNRM_OFF;
    int*   ccol = (int*)(ws + CCOL_OFF);
    int*   offs = (int*)(ws + OFFS_OFF);
    float* f    = ws + F_OFF;
    float* r1   = ws + R1_OFF;
    float* out  = (float*)d_out;

    hipMemsetAsync(r1, 0, (size_t)NG * 1024 * sizeof(float), stream);
    hipMemsetAsync(out, 0, (size_t)out_size * sizeof(float), stream);

    k_csr <<<NG, 256, 0, stream>>>(ei0, ei1, ei2, ea0, ea1, ea2, cnrm, ccol, offs);
    k_xw  <<<dim3(3, NG), 256, 0, stream>>>(x0, x1, x2, gc1w, xw0, xw1);
    k_conv<<<NG, 256, 0, stream>>>(xw0, xw1, cnrm, ccol, offs, gc1b, gc4w, gc4b, f);
    k_fc1 <<<dim3(2, 8, 16), 256, 0, stream>>>(f, fc1w, r1);
    k_fc2 <<<dim3(3, 8, 8), 256, 0, stream>>>(r1, fc1b, fc2w, fc2b, out);
}

// Round 2
// 257.460 us; speedup vs baseline: 1.6143x; 1.6143x over previous
//
#include <hip/hip_runtime.h>

// Siamese GeoCheby, round 2:
//  - segment_sum(norm * x[col]) @ W == segment_sum(norm * (x@W)[col])  (H=16 aggregation)
//  - xw and fc1 GEMMs on bf16 MFMA 16x16x32, fragments loaded straight from global
//  - CSR build fused into k_conv, CSR kept in LDS (4B/edge packed), parallel scan
//  - split-K partials via plain stores + reduce kernels (no atomics, no memsets)

#define NN   268
#define EE   8576
#define NG   192
#define FDIM 4288        // 268*16
#define KCH  134         // 4288/32 K-chunks for fc1

typedef __bf16 bf16_t;
typedef bf16_t bf16x8 __attribute__((ext_vector_type(8)));
typedef bf16_t bf16x4 __attribute__((ext_vector_type(4)));
typedef float  f32x4  __attribute__((ext_vector_type(4)));

// ---- workspace layout (float offsets) ----
#define XW0_OFF  0                                   // 192*4288 f32
#define XW1_OFF  (XW0_OFF + (size_t)NG * FDIM)       // 192*4288 f32; later reused as R1P
#define WB_OFF   (XW1_OFF + (size_t)NG * FDIM)       // 1024*4288 bf16 = 2195456 f32
#define FB_OFF   (WB_OFF + 2195456)                  // 192*4288 bf16 = 411648 f32
#define WXT_OFF  (FB_OFF + 411648)                   // 2*9*64*8 bf16 = 4608 f32
#define H1_OFF   (WXT_OFF + 4608)                    // 192*1024 f32
#define WS_END   (H1_OFF + 196608)                   // ~17.8 MB total
#define R1P_OFF  XW1_OFF                             // 4*192*1024 f32 (aliases XW1, dead by then)
#define R2P_OFF  XW0_OFF                             // 8*192*512 f32 (aliases XW0, dead by then)

#define NCASTB 2144    // 2144 blocks * 2048 elems = 4390912 = 1024*4288

// ---------------------------------------------------------------------------
// K0: cast fc1_w to bf16 (row-major) + build MFMA B-fragments of [w0|w1]
// ---------------------------------------------------------------------------
__global__ __launch_bounds__(256) void k_prep(
    const float* __restrict__ fc1w, const float* __restrict__ gc1w,
    bf16_t* __restrict__ wb, bf16_t* __restrict__ wxt)
{
    if (blockIdx.x < NCASTB) {
        const size_t base = ((size_t)blockIdx.x * 256 + threadIdx.x) * 8;
        const float4 a = *(const float4*)(fc1w + base);
        const float4 b = *(const float4*)(fc1w + base + 4);
        bf16x8 v;
        v[0] = (bf16_t)a.x; v[1] = (bf16_t)a.y; v[2] = (bf16_t)a.z; v[3] = (bf16_t)a.w;
        v[4] = (bf16_t)b.x; v[5] = (bf16_t)b.y; v[6] = (bf16_t)b.z; v[7] = (bf16_t)b.w;
        *(bf16x8*)(wb + base) = v;
    } else {
        // B-fragment for 16x16x32: lane holds B[k = (lane>>4)*8 + j][n = lane&15]
        // wxt[nt][chunk][lane][8], nt in {0,1} selects w0/w1 column block
        for (int idx = threadIdx.x; idx < 2 * 9 * 64; idx += 256) {
            const int lane = idx & 63, chunk = (idx >> 6) % 9, nt = idx / (9 * 64);
            const int n = lane & 15, q = lane >> 4;
            bf16x8 v;
#pragma unroll
            for (int j = 0; j < 8; ++j) {
                const int k = chunk * 32 + q * 8 + j;
                v[j] = (k < NN) ? (bf16_t)gc1w[nt * FDIM + k * 16 + n] : (bf16_t)0.f;
            }
            *(bf16x8*)(wxt + (size_t)idx * 8) = v;
        }
    }
}

// ---------------------------------------------------------------------------
// K1: xw = x @ [w0|w1] via MFMA. One wave per (16-row m-tile, graph).
// A-fragments loaded from global fp32 + converted; B-fragments precomputed.
// ---------------------------------------------------------------------------
__global__ __launch_bounds__(64) void k_xw(
    const float* __restrict__ x0, const float* __restrict__ x1, const float* __restrict__ x2,
    const bf16_t* __restrict__ wxt, float* __restrict__ xw0, float* __restrict__ xw1)
{
    const int g = blockIdx.y;
    const int br = g >> 6, b = g & 63;
    const float* x = ((br == 0) ? x0 : (br == 1) ? x1 : x2) + (size_t)b * (NN * NN);
    const int lane = threadIdx.x;
    const int q = lane >> 4, nlo = lane & 15;
    const int mrow = blockIdx.x * 16 + nlo;          // A row this lane feeds
    const bool mvalid = (mrow < NN);
    const float* xrow = x + (size_t)mrow * NN;

    f32x4 acc0 = {0.f, 0.f, 0.f, 0.f}, acc1 = {0.f, 0.f, 0.f, 0.f};
    for (int ch = 0; ch < 9; ++ch) {
        const int k0 = ch * 32 + q * 8;
        float4 p0 = make_float4(0.f, 0.f, 0.f, 0.f);
        float4 p1 = make_float4(0.f, 0.f, 0.f, 0.f);
        if (mvalid) {
            if (k0 < NN)     p0 = *(const float4*)(xrow + k0);
            if (k0 + 4 < NN) p1 = *(const float4*)(xrow + k0 + 4);
        }
        bf16x8 a;
        a[0] = (bf16_t)p0.x; a[1] = (bf16_t)p0.y; a[2] = (bf16_t)p0.z; a[3] = (bf16_t)p0.w;
        a[4] = (bf16_t)p1.x; a[5] = (bf16_t)p1.y; a[6] = (bf16_t)p1.z; a[7] = (bf16_t)p1.w;
        const bf16x8 b0 = *(const bf16x8*)(wxt + (size_t)(ch * 64 + lane) * 8);
        const bf16x8 b1 = *(const bf16x8*)(wxt + (size_t)(576 + ch * 64 + lane) * 8);
        acc0 = __builtin_amdgcn_mfma_f32_16x16x32_bf16(a, b0, acc0, 0, 0, 0);
        acc1 = __builtin_amdgcn_mfma_f32_16x16x32_bf16(a, b1, acc1, 0, 0, 0);
    }
    // C/D: col = lane&15, row = (lane>>4)*4 + r
    const int col = nlo;
#pragma unroll
    for (int r = 0; r < 4; ++r) {
        const int row = blockIdx.x * 16 + q * 4 + r;
        if (row < NN) {
            xw0[((size_t)g * NN + row) * 16 + col] = acc0[r];
            xw1[((size_t)g * NN + row) * 16 + col] = acc1[r];
        }
    }
}

// ---------------------------------------------------------------------------
// K2: fused CSR build (LDS) + conv1(relu) + H1 GEMM + conv2 -> f (bf16)
// Edge record: (col << 16) | bf16bits(norm) -> 4 B/edge, all in LDS.
// ---------------------------------------------------------------------------
__global__ __launch_bounds__(256) void k_conv(
    const int* __restrict__ ei0, const int* __restrict__ ei1, const int* __restrict__ ei2,
    const float* __restrict__ ea0, const float* __restrict__ ea1, const float* __restrict__ ea2,
    const float* __restrict__ xw0, const float* __restrict__ xw1,
    const float* __restrict__ gc1b, const float* __restrict__ gc4w,
    const float* __restrict__ gc4b, bf16_t* __restrict__ fout)
{
    const int g = blockIdx.x;
    const int br = g >> 6, b = g & 63;
    const int*   ei = (br == 0) ? ei0 : (br == 1) ? ei1 : ei2;
    const float* ea = (br == 0) ? ea0 : (br == 1) ? ea1 : ea2;
    const int*   rowp = ei + (size_t)b * (2 * EE);
    const int*   colp = rowp + EE;
    const float* eap  = ea + (size_t)b * EE;

    __shared__ unsigned int e_s[EE];               // 34.3 KB packed edges
    __shared__ __align__(16) bf16_t A_s[FDIM];     // 8.6 KB (xw1, then H1)
    __shared__ __align__(16) bf16_t S_s[FDIM];     // 8.6 KB (h)
    __shared__ float degS[NN];
    __shared__ int   cntS[NN];
    __shared__ int   offS[NN + 1];
    __shared__ int   curS[NN];
    __shared__ float w4_s[512];
    __shared__ float b1_s[16];
    __shared__ float b4_s[16];
    const int tid = threadIdx.x;

    for (int n = tid; n < NN; n += 256) { degS[n] = 0.f; cntS[n] = 0; }
    for (int i = tid; i < 512; i += 256) w4_s[i] = gc4w[i];
    if (tid < 16) { b1_s[tid] = gc1b[tid]; b4_s[tid] = gc4b[tid]; }
    // stage A_s = bf16(xw1[g])
    {
        const float4* src = (const float4*)(xw1 + (size_t)g * FDIM);
        for (int i = tid; i < FDIM / 4; i += 256) {
            const float4 v = src[i];
            bf16x4 o; o[0] = (bf16_t)v.x; o[1] = (bf16_t)v.y; o[2] = (bf16_t)v.z; o[3] = (bf16_t)v.w;
            *(bf16x4*)&A_s[i * 4] = o;
        }
    }
    __syncthreads();
    // pass 1: degree + count
    for (int e = tid; e < EE; e += 256) {
        const int r = rowp[e];
        atomicAdd(&degS[r], eap[e]);
        atomicAdd(&cntS[r], 1);
    }
    // inclusive Hillis-Steele scan of cntS (268 elems, 256 threads, in-place)
    for (int st = 1; st < NN; st <<= 1) {
        __syncthreads();
        int v0 = 0, v1 = 0;
        const int n0i = tid, n1i = tid + 256;
        if (n0i < NN) { v0 = cntS[n0i]; if (n0i >= st) v0 += cntS[n0i - st]; }
        if (n1i < NN) { v1 = cntS[n1i]; if (n1i >= st) v1 += cntS[n1i - st]; }
        __syncthreads();
        if (n0i < NN) cntS[n0i] = v0;
        if (n1i < NN) cntS[n1i] = v1;
    }
    __syncthreads();
    for (int n = tid; n < NN; n += 256) offS[n + 1] = cntS[n];
    if (tid == 0) offS[0] = 0;
    __syncthreads();
    for (int n = tid; n < NN; n += 256) {
        curS[n] = offS[n];
        const float d = degS[n];
        degS[n] = (d > 0.f) ? rsqrtf(d) : 0.f;     // degS becomes dis
    }
    __syncthreads();
    // pass 2: scatter packed edges into LDS CSR
    for (int e = tid; e < EE; e += 256) {
        const int r = rowp[e], c = colp[e];
        const float nv = -eap[e] * degS[r] * degS[c];
        union { float f; unsigned u; } cv; cv.f = nv;
        const unsigned bits = (cv.u + 0x7fffu + ((cv.u >> 16) & 1u)) >> 16;   // RNE to bf16
        const int pos = atomicAdd(&curS[r], 1);
        e_s[pos] = ((unsigned)c << 16) | bits;
    }
    __syncthreads();

    const int j4 = tid & 3, nl = tid >> 2;
    const bf16x4* A4 = (const bf16x4*)A_s;
    const float4* xw0g = (const float4*)(xw0 + (size_t)g * FDIM);

    // conv1: h = relu(xw0 + gather(A_s) + b1) -> S_s (bf16)
    for (int n = nl; n < NN; n += 64) {
        const int s = offS[n], e = offS[n + 1];
        float ax = 0.f, ay = 0.f, az = 0.f, aw = 0.f;
        int i = s;
        for (; i + 1 < e; i += 2) {
            const unsigned p0 = e_s[i], p1 = e_s[i + 1];
            const float w0 = __uint_as_float(p0 << 16);
            const float w1 = __uint_as_float(p1 << 16);
            const bf16x4 a0 = A4[(p0 >> 16) * 4 + j4];
            const bf16x4 a1 = A4[(p1 >> 16) * 4 + j4];
            ax += w0 * (float)a0[0] + w1 * (float)a1[0];
            ay += w0 * (float)a0[1] + w1 * (float)a1[1];
            az += w0 * (float)a0[2] + w1 * (float)a1[2];
            aw += w0 * (float)a0[3] + w1 * (float)a1[3];
        }
        if (i < e) {
            const unsigned p0 = e_s[i];
            const float w0 = __uint_as_float(p0 << 16);
            const bf16x4 a0 = A4[(p0 >> 16) * 4 + j4];
            ax += w0 * (float)a0[0]; ay += w0 * (float)a0[1];
            az += w0 * (float)a0[2]; aw += w0 * (float)a0[3];
        }
        const float4 xv = xw0g[n * 4 + j4];
        bf16x4 h;
        h[0] = (bf16_t)fmaxf(xv.x + ax + b1_s[j4 * 4 + 0], 0.f);
        h[1] = (bf16_t)fmaxf(xv.y + ay + b1_s[j4 * 4 + 1], 0.f);
        h[2] = (bf16_t)fmaxf(xv.z + az + b1_s[j4 * 4 + 2], 0.f);
        h[3] = (bf16_t)fmaxf(xv.w + aw + b1_s[j4 * 4 + 3], 0.f);
        *(bf16x4*)&S_s[n * 16 + j4 * 4] = h;
    }
    __syncthreads();

    // H1 = h @ w4[1] -> A_s
    for (int idx = tid; idx < FDIM; idx += 256) {
        const int n = idx >> 4, j = idx & 15;
        float a1 = 0.f;
#pragma unroll
        for (int k = 0; k < 16; ++k) a1 += (float)S_s[n * 16 + k] * w4_s[256 + k * 16 + j];
        A_s[idx] = (bf16_t)a1;
    }
    __syncthreads();

    // conv2: f = h @ w4[0] + b4 + gather(H1)  -> fout (bf16)
    for (int n = nl; n < NN; n += 64) {
        const int s = offS[n], e = offS[n + 1];
        float ax = 0.f, ay = 0.f, az = 0.f, aw = 0.f;
        int i = s;
        for (; i + 1 < e; i += 2) {
            const unsigned p0 = e_s[i], p1 = e_s[i + 1];
            const float w0 = __uint_as_float(p0 << 16);
            const float w1 = __uint_as_float(p1 << 16);
            const bf16x4 a0 = A4[(p0 >> 16) * 4 + j4];
            const bf16x4 a1 = A4[(p1 >> 16) * 4 + j4];
            ax += w0 * (float)a0[0] + w1 * (float)a1[0];
            ay += w0 * (float)a0[1] + w1 * (float)a1[1];
            az += w0 * (float)a0[2] + w1 * (float)a1[2];
            aw += w0 * (float)a0[3] + w1 * (float)a1[3];
        }
        if (i < e) {
            const unsigned p0 = e_s[i];
            const float w0 = __uint_as_float(p0 << 16);
            const bf16x4 a0 = A4[(p0 >> 16) * 4 + j4];
            ax += w0 * (float)a0[0]; ay += w0 * (float)a0[1];
            az += w0 * (float)a0[2]; aw += w0 * (float)a0[3];
        }
        float h0[4];
#pragma unroll
        for (int c2 = 0; c2 < 4; ++c2) h0[c2] = b4_s[j4 * 4 + c2];
#pragma unroll
        for (int k = 0; k < 16; ++k) {
            const float sv = (float)S_s[n * 16 + k];
#pragma unroll
            for (int c2 = 0; c2 < 4; ++c2) h0[c2] += sv * w4_s[k * 16 + j4 * 4 + c2];
        }
        bf16x4 o;
        o[0] = (bf16_t)(h0[0] + ax); o[1] = (bf16_t)(h0[1] + ay);
        o[2] = (bf16_t)(h0[2] + az); o[3] = (bf16_t)(h0[3] + aw);
        *(bf16x4*)(fout + (size_t)g * FDIM + n * 16 + j4 * 4) = o;
    }
}

// ---------------------------------------------------------------------------
// K3: fc1 MFMA: r1p[kz][192][1024] = f_bf16 @ w_bf16^T (K-slice), plain stores
// grid (12 m-tiles, 4 n-blocks, 4 kz), wave = 1 m-tile x 4 n-tiles
// ---------------------------------------------------------------------------
__global__ __launch_bounds__(256) void k_fc1(
    const bf16_t* __restrict__ fb, const bf16_t* __restrict__ wb, float* __restrict__ r1p)
{
    const int mt = blockIdx.x, nb = blockIdx.y, kz = blockIdx.z;
    const int wid = threadIdx.x >> 6, lane = threadIdx.x & 63;
    const int q = lane >> 4, nlo = lane & 15;
    const int n0 = nb * 256 + wid * 64;
    const int cstart = (kz < 2) ? kz * 34 : 68 + (kz - 2) * 33;  // 0,34,68,101
    const int ccnt   = (kz < 2) ? 34 : 33;

    const bf16_t* arow = fb + (size_t)(mt * 16 + nlo) * FDIM + q * 8;
    const bf16_t* brow = wb + (size_t)(n0 + nlo) * FDIM + q * 8;
    f32x4 acc[4];
#pragma unroll
    for (int t = 0; t < 4; ++t) { acc[t][0]=0.f; acc[t][1]=0.f; acc[t][2]=0.f; acc[t][3]=0.f; }

    for (int ch = 0; ch < ccnt; ++ch) {
        const size_t ko = (size_t)(cstart + ch) * 32;
        const bf16x8 a = *(const bf16x8*)(arow + ko);
#pragma unroll
        for (int t = 0; t < 4; ++t) {
            const bf16x8 bv = *(const bf16x8*)(brow + (size_t)t * 16 * FDIM + ko);
            acc[t] = __builtin_amdgcn_mfma_f32_16x16x32_bf16(a, bv, acc[t], 0, 0, 0);
        }
    }
    float* outp = r1p + (size_t)kz * (NG * 1024);
#pragma unroll
    for (int t = 0; t < 4; ++t)
#pragma unroll
        for (int r = 0; r < 4; ++r)
            outp[(size_t)(mt * 16 + q * 4 + r) * 1024 + n0 + t * 16 + nlo] = acc[t][r];
}

// K4: h1 = relu(sum_kz r1p + fc1_b)
__global__ __launch_bounds__(256) void k_red1(
    const float* __restrict__ r1p, const float* __restrict__ b1, float* __restrict__ h1)
{
    const size_t i = ((size_t)blockIdx.x * 256 + threadIdx.x) * 4;
    const size_t S = (size_t)NG * 1024;
    float4 s0 = *(const float4*)(r1p + i);
    const float4 s1 = *(const float4*)(r1p + S + i);
    const float4 s2 = *(const float4*)(r1p + 2 * S + i);
    const float4 s3 = *(const float4*)(r1p + 3 * S + i);
    const float4 bb = *(const float4*)(b1 + (i & 1023));
    float4 o;
    o.x = fmaxf(s0.x + s1.x + s2.x + s3.x + bb.x, 0.f);
    o.y = fmaxf(s0.y + s1.y + s2.y + s3.y + bb.y, 0.f);
    o.z = fmaxf(s0.z + s1.z + s2.z + s3.z + bb.z, 0.f);
    o.w = fmaxf(s0.w + s1.w + s2.w + s3.w + bb.w, 0.f);
    *(float4*)(h1 + i) = o;
}

// K5: fc2 partials: r2p[kz][192][512] = h1 @ fc2_w^T (K-slice), plain stores
__global__ __launch_bounds__(256) void k_fc2(
    const float* __restrict__ h1, const float* __restrict__ w2, float* __restrict__ r2p)
{
    const int m0 = blockIdx.x * 64;
    const int n0 = blockIdx.y * 64;
    const int kb = blockIdx.z * 128;
    __shared__ float rs[64][68];
    __shared__ float wss[64][68];
    const int tid = threadIdx.x;
    const int mt = tid & 15, nt = tid >> 4;
    float acc[4][4];
#pragma unroll
    for (int i = 0; i < 4; ++i)
#pragma unroll
        for (int j = 0; j < 4; ++j) acc[i][j] = 0.f;

    for (int kc = 0; kc < 128; kc += 64) {
        __syncthreads();
        for (int idx = tid; idx < 1024; idx += 256) {
            const int r = idx >> 4, qq = idx & 15;
            const int gk = kb + kc + qq * 4;
            *(float4*)&rs[r][qq * 4]  = *(const float4*)(h1 + (size_t)(m0 + r) * 1024 + gk);
            *(float4*)&wss[r][qq * 4] = *(const float4*)(w2 + (size_t)(n0 + r) * 1024 + gk);
        }
        __syncthreads();
        for (int kq = 0; kq < 16; ++kq) {
            float4 av[4], bv[4];
#pragma unroll
            for (int i = 0; i < 4; ++i) av[i] = *(const float4*)&rs[mt + 16 * i][kq * 4];
#pragma unroll
            for (int j = 0; j < 4; ++j) bv[j] = *(const float4*)&wss[nt + 16 * j][kq * 4];
#pragma unroll
            for (int i = 0; i < 4; ++i)
#pragma unroll
                for (int j = 0; j < 4; ++j)
                    acc[i][j] += av[i].x * bv[j].x + av[i].y * bv[j].y +
                                 av[i].z * bv[j].z + av[i].w * bv[j].w;
        }
    }
    float* outp = r2p + (size_t)blockIdx.z * (NG * 512);
#pragma unroll
    for (int i = 0; i < 4; ++i)
#pragma unroll
        for (int j = 0; j < 4; ++j)
            outp[(size_t)(m0 + mt + 16 * i) * 512 + n0 + nt + 16 * j] = acc[i][j];
}

// K6: out = sum_kz r2p + fc2_b
__global__ __launch_bounds__(256) void k_red2(
    const float* __restrict__ r2p, const float* __restrict__ b2, float* __restrict__ out)
{
    const size_t i = ((size_t)blockIdx.x * 256 + threadIdx.x) * 4;
    const size_t S = (size_t)NG * 512;
    float4 s = *(const float4*)(r2p + i);
#pragma unroll
    for (int k = 1; k < 8; ++k) {
        const float4 t = *(const float4*)(r2p + k * S + i);
        s.x += t.x; s.y += t.y; s.z += t.z; s.w += t.w;
    }
    const float4 bb = *(const float4*)(b2 + (i & 511));
    s.x += bb.x; s.y += bb.y; s.z += bb.z; s.w += bb.w;
    *(float4*)(out + i) = s;
}

// ---------------------------------------------------------------------------
extern "C" void kernel_launch(void* const* d_in, const int* in_sizes, int n_in,
                              void* d_out, int out_size, void* d_ws, size_t ws_size,
                              hipStream_t stream)
{
    const float* x0   = (const float*)d_in[0];
    const float* x1   = (const float*)d_in[1];
    const float* x2   = (const float*)d_in[2];
    const int*   ei0  = (const int*)d_in[3];
    const int*   ei1  = (const int*)d_in[4];
    const int*   ei2  = (const int*)d_in[5];
    const float* ea0  = (const float*)d_in[6];
    const float* ea1  = (const float*)d_in[7];
    const float* ea2  = (const float*)d_in[8];
    const float* gc1w = (const float*)d_in[9];
    const float* gc1b = (const float*)d_in[10];
    const float* gc4w = (const float*)d_in[11];
    const float* gc4b = (const float*)d_in[12];
    const float* fc1w = (const float*)d_in[13];
    const float* fc1b = (const float*)d_in[14];
    const float* fc2w = (const float*)d_in[15];
    const float* fc2b = (const float*)d_in[16];

    float*  ws  = (float*)d_ws;
    float*  xw0 = ws + XW0_OFF;
    float*  xw1 = ws + XW1_OFF;
    bf16_t* wb  = (bf16_t*)(ws + WB_OFF);
    bf16_t* fb  = (bf16_t*)(ws + FB_OFF);
    bf16_t* wxt = (bf16_t*)(ws + WXT_OFF);
    float*  h1  = ws + H1_OFF;
    float*  r1p = ws + R1P_OFF;   // aliases xw1 (dead after k_conv)
    float*  r2p = ws + R2P_OFF;   // aliases xw0 (dead after k_conv)
    float*  out = (float*)d_out;

    k_prep<<<NCASTB + 1, 256, 0, stream>>>(fc1w, gc1w, wb, wxt);
    k_xw  <<<dim3(17, NG), 64, 0, stream>>>(x0, x1, x2, wxt, xw0, xw1);
    k_conv<<<NG, 256, 0, stream>>>(ei0, ei1, ei2, ea0, ea1, ea2,
                                   xw0, xw1, gc1b, gc4w, gc4b, fb);
    k_fc1 <<<dim3(12, 4, 4), 256, 0, stream>>>(fb, wb, r1p);
    k_red1<<<NG, 256, 0, stream>>>(r1p, fc1b, h1);
    k_fc2 <<<dim3(3, 8, 8), 256, 0, stream>>>(h1, fc2w, r2p);
    k_red2<<<96, 256, 0, stream>>>(r2p, fc2b, out);
}